// Round 8
// baseline (4198.603 us; speedup 1.0000x reference)
//
#include <hip/hip_runtime.h>
#include <stdint.h>

#define T_DIM 4096
#define N_DIM 32768
#define D_DIM 1024
#define QB 64
#define KB 32
#define KSPLIT 4
#define ITERS (N_DIM / KSPLIT / KB)      // 256
#define NKEYS_PER (N_DIM / KSPLIT)       // 8192
#define NBLOCKS ((T_DIM / QB) * KSPLIT)  // 256 = 1 block/CU

typedef _Float16 f16;
typedef _Float16 f16x8 __attribute__((ext_vector_type(8)));
typedef _Float16 f16x4 __attribute__((ext_vector_type(4)));
typedef float f32x4 __attribute__((ext_vector_type(4)));

#define SWZ(q, k0) ((k0) ^ ((((q) >> 2) & 3) << 2))
#define PEPS 2.061e-9f   // e^-20: V-skip threshold (error bound ~7e-5 << 0.05 slack)

struct __align__(16) Lds {
  f16   K[2][KB * D_DIM];   // 131072 B : double-buffered key tile (swizzled)
  float Spart[2][QB][40];   //  20480 B : per-d-half score partials
  f16   P[QB][40];          //   5120 B
  float srow[QB];           //    256 B
  float linv[QB];           //    256 B
  int   vflag[2];           // V-pass flags (ping-pong)
  int   pad[2];
};                          // 157200 B total -> 1 block/CU

// ---- precompute: E (fp32 row-major) -> E16 (fp16 row-major)
__global__ void e16_build(const float* __restrict__ E, f16* __restrict__ E16) {
  size_t i8 = (size_t)(blockIdx.x * 256 + threadIdx.x) * 8;
  float4 a = *(const float4*)(E + i8);
  float4 b = *(const float4*)(E + i8 + 4);
  f16x8 v = {(f16)a.x,(f16)a.y,(f16)a.z,(f16)a.w,
             (f16)b.x,(f16)b.y,(f16)b.z,(f16)b.w};
  *(f16x8*)(E16 + i8) = v;
}

__device__ __forceinline__ void gl_lds16(const void* g, void* l) {
  // CK-style addrspace casts (flat->AS1 is identity; flat LDS low bits = offset)
  auto* gp = reinterpret_cast<const __attribute__((address_space(1))) uint32_t*>(
      reinterpret_cast<uintptr_t>(g));
  auto* lp = reinterpret_cast<__attribute__((address_space(3))) uint32_t*>(
      reinterpret_cast<uintptr_t>(l));
  __builtin_amdgcn_global_load_lds(gp, lp, 16, 0, 0);
}

// 512 thr = 8 waves, 1 block/CU (157 KB LDS). Wave (qt=w>>1, dh=w&1) does QK^T
// over d-half dh for q-subtile qt; wave w owns d-slice w*128 for PV.
// K tile staged 2 iters ahead via global_load_lds into swizzled-linear LDS
// (source pre-swizzled: byte a -> a ^ (((a>>11)&7)<<4), involution; read side
// applies the same XOR). V is read from the SAME tile (u16 gathers) -> zero
// V global traffic; gated by tile-wide max-p (V-skip).
// Frag maps (verified r1-r6): A row=lane&15, k=(lane>>4)*8+j; B col=lane&15;
// C row=4*(lane>>4)+r, col=lane&15.
__global__ __launch_bounds__(512, 1)
void cboe_attn(const float* __restrict__ X, const f16* __restrict__ E16,
               f16* __restrict__ O16, float* __restrict__ ML)
{
  extern __shared__ char smem_raw[];
  Lds& L = *reinterpret_cast<Lds*>(smem_raw);
  const int tid  = threadIdx.x;
  const int lane = tid & 63;
  const int w    = tid >> 6;
  const int c    = lane & 15;
  const int g    = lane >> 4;
  const int qt   = w >> 1;       // QK q-subtile
  const int dh   = w & 1;        // QK d-half
  const int wd   = w * 64 * 2;   // PV d-slice = w*128
  const int qtile = blockIdx.x & 63;
  const int ks    = blockIdx.x >> 6;           // natural mapping (r2: best FETCH)
  const int qb    = qtile * QB;
  const size_t key0 = (size_t)ks * NKEYS_PER;
  const int sq    = tid >> 3;    // softmax: q row 0..63
  const int kslot = tid & 7;     // softmax: 4 keys each

  // Q frags (B-operand): qf[kc] = X[qb+qt*16+c][dh*512 + kc*32 + g*8 ..+7]
  f16x8 qf[16];
  {
    const float* qrow = X + (size_t)(qb + qt*16 + c) * D_DIM + dh*512;
    #pragma unroll
    for (int kc = 0; kc < 16; ++kc) {
      float4 a = *(const float4*)(qrow + kc*32 + g*8);
      float4 b = *(const float4*)(qrow + kc*32 + g*8 + 4);
      qf[kc] = (f16x8){(f16)a.x,(f16)a.y,(f16)a.z,(f16)a.w,
                       (f16)b.x,(f16)b.y,(f16)b.z,(f16)b.w};
    }
  }

  f32x4 acc[4][8];
  #pragma unroll
  for (int q2 = 0; q2 < 4; ++q2)
    #pragma unroll
    for (int dt = 0; dt < 8; ++dt) acc[q2][dt] = (f32x4){0.f,0.f,0.f,0.f};

  float m_run = -1.0e30f, l_run = 0.0f;

  if (tid == 0) { L.vflag[0] = 0; L.vflag[1] = 0; }
  __syncthreads();

  #define STAGE(IT) do {                                                      \
    const char* gtile_ = (const char*)(E16 + (key0 + (size_t)(IT)*KB)*D_DIM); \
    char* lbase_ = (char*)&L.K[(IT) & 1][0] + w*8192;                         \
    _Pragma("unroll")                                                         \
    for (int r_ = 0; r_ < 8; ++r_) {                                          \
      uint32_t a_ = (uint32_t)(w*8192 + r_*1024 + lane*16);                   \
      uint32_t s_ = a_ ^ (((a_ >> 11) & 7) << 4);                             \
      gl_lds16(gtile_ + s_, lbase_ + r_*1024);                                \
    }                                                                         \
  } while (0)

  STAGE(0);
  STAGE(1);

  for (int it = 0; it < ITERS; ++it) {
    const f16* KL = &L.K[it & 1][0];

    // ---- B0: own stage(it) landed (8 newest = stage(it+1)) + all waves'
    asm volatile("s_waitcnt vmcnt(8)" ::: "memory");
    __builtin_amdgcn_s_barrier();
    asm volatile("" ::: "memory");

    // ---- phase A: QK^T over d-half dh, q-subtile qt (K from swizzled LDS)
    #pragma unroll
    for (int kt = 0; kt < 2; ++kt) {
      const int keyb = (kt*16 + c) << 10;
      const int sxor = (c & 7) << 3;
      f32x4 s = (f32x4){0.f,0.f,0.f,0.f};
      __builtin_amdgcn_s_setprio(1);
      #pragma unroll
      for (int kc = 0; kc < 16; ++kc) {
        f16x8 ak = *(const f16x8*)&KL[keyb + ((dh*512 + kc*32 + g*8) ^ sxor)];
        s = __builtin_amdgcn_mfma_f32_16x16x32_f16(ak, qf[kc], s, 0, 0, 0);
      }
      __builtin_amdgcn_s_setprio(0);
      const int q = qt*16 + c;
      *(f32x4*)&L.Spart[dh][q][SWZ(q, kt*16 + g*4)] = s;
    }

    // ---- B1
    asm volatile("s_waitcnt lgkmcnt(0)" ::: "memory");
    __builtin_amdgcn_s_barrier();
    asm volatile("" ::: "memory");

    // ---- softmax: 8 threads/row, fold 2 d-halves
    f32x4 sv = *(const f32x4*)&L.Spart[0][sq][SWZ(sq, kslot*4)];
    sv += *(const f32x4*)&L.Spart[1][sq][SWZ(sq, kslot*4)];
    float tm = fmaxf(fmaxf(sv[0],sv[1]), fmaxf(sv[2],sv[3]));
    tm = fmaxf(tm, __shfl_xor(tm, 1));
    tm = fmaxf(tm, __shfl_xor(tm, 2));
    tm = fmaxf(tm, __shfl_xor(tm, 4));
    const bool upd = tm > m_run + 8.0f;            // T13 defer-max
    const float mn = upd ? tm : m_run;
    const float scale = upd ? __expf(m_run - mn) : 1.0f;
    float p0 = __expf(sv[0]-mn), p1 = __expf(sv[1]-mn);
    float p2 = __expf(sv[2]-mn), p3 = __expf(sv[3]-mn);
    *(f16x4*)&L.P[sq][kslot*4] = (f16x4){(f16)p0,(f16)p1,(f16)p2,(f16)p3};
    float ps = (p0+p1)+(p2+p3);
    ps += __shfl_xor(ps, 1);
    ps += __shfl_xor(ps, 2);
    ps += __shfl_xor(ps, 4);
    l_run = l_run * scale + ps;
    m_run = mn;
    if (kslot == 0) L.srow[sq] = scale;
    bool big = (p0>PEPS)|(p1>PEPS)|(p2>PEPS)|(p3>PEPS);
    if (__any(big) && lane == 0) atomicOr(&L.vflag[it & 1], 1);
    if (tid == 0) L.vflag[(it+1) & 1] = 0;

    // ---- B2
    asm volatile("s_waitcnt lgkmcnt(0)" ::: "memory");
    __builtin_amdgcn_s_barrier();
    asm volatile("" ::: "memory");

    const int vpass = L.vflag[it & 1];   // block-uniform

    // rescale (gated)
    #pragma unroll
    for (int q2 = 0; q2 < 4; ++q2) {
      f32x4 sc = *(const f32x4*)&L.srow[q2*16 + g*4];
      bool need = (sc[0]!=1.f)|(sc[1]!=1.f)|(sc[2]!=1.f)|(sc[3]!=1.f);
      if (__any(need)) {
        #pragma unroll
        for (int dt = 0; dt < 8; ++dt) {
          acc[q2][dt][0]*=sc[0]; acc[q2][dt][1]*=sc[1];
          acc[q2][dt][2]*=sc[2]; acc[q2][dt][3]*=sc[3];
        }
      }
    }

    if (vpass) {
      // V gathers from the SAME staged tile: V[key][d], swizzle-aware.
      // half-idx = key*1024 + d, key = g*8+j -> XOR reduces to d ^ (j<<3).
      f16x8 bv[8];
      #pragma unroll
      for (int dt = 0; dt < 8; ++dt) {
        const int dtl = wd + dt*16 + c;
        #pragma unroll
        for (int j = 0; j < 8; ++j)
          bv[dt][j] = KL[((g*8 + j) << 10) + (dtl ^ (j << 3))];
      }
      // B3: gathers done in regs before stage overwrites this buffer
      asm volatile("s_waitcnt lgkmcnt(0)" ::: "memory");
      __builtin_amdgcn_s_barrier();
      asm volatile("" ::: "memory");
      if (it + 2 < ITERS) STAGE(it + 2);
      __builtin_amdgcn_s_setprio(1);
      #pragma unroll
      for (int q2 = 0; q2 < 4; ++q2) {
        f16x8 ap = *(const f16x8*)&L.P[q2*16 + c][g*8];
        #pragma unroll
        for (int dt = 0; dt < 8; ++dt)
          acc[q2][dt] = __builtin_amdgcn_mfma_f32_16x16x32_f16(ap, bv[dt], acc[q2][dt], 0, 0, 0);
      }
      __builtin_amdgcn_s_setprio(0);
    } else {
      if (it + 2 < ITERS) STAGE(it + 2);   // safe: no reads of buf after B2
    }
  }

  // ---- epilogue: normalized f16 partials + (m,l)
  if (kslot == 0) {
    size_t qg = (size_t)qb + sq;
    ML[((size_t)ks * T_DIM + qg) * 2 + 0] = m_run;
    ML[((size_t)ks * T_DIM + qg) * 2 + 1] = l_run;
    L.linv[sq] = 1.0f / l_run;
  }
  __syncthreads();
  #pragma unroll
  for (int q2 = 0; q2 < 4; ++q2) {
    f32x4 li = *(const f32x4*)&L.linv[q2*16 + g*4];
    #pragma unroll
    for (int dt = 0; dt < 8; ++dt)
      #pragma unroll
      for (int r = 0; r < 4; ++r)
        O16[((size_t)ks * T_DIM + qb + q2*16 + 4*g + r) * D_DIM + wd + dt*16 + c] =
            (f16)(acc[q2][dt][r] * li[r]);
  }
}

// ---- combine: out = sum_ks w_ks * O_ks, w_ks = l_ks e^{m_ks-M} / sum l e^{m-M}
__global__ void combine(const f16* __restrict__ O16, const float* __restrict__ ML,
                        float* __restrict__ Out) {
  int q  = blockIdx.x;
  int d0 = threadIdx.x * 4;
  float m[KSPLIT], l[KSPLIT];
  float M = -1.0e30f;
  #pragma unroll
  for (int ks = 0; ks < KSPLIT; ++ks) {
    m[ks] = ML[((size_t)ks * T_DIM + q) * 2 + 0];
    l[ks] = ML[((size_t)ks * T_DIM + q) * 2 + 1];
    M = fmaxf(M, m[ks]);
  }
  float W = 0.f, wk[KSPLIT];
  #pragma unroll
  for (int ks = 0; ks < KSPLIT; ++ks) {
    wk[ks] = l[ks] * __expf(m[ks] - M);
    W += wk[ks];
  }
  float inv = 1.0f / W;
  float o0 = 0.f, o1 = 0.f, o2 = 0.f, o3 = 0.f;
  #pragma unroll
  for (int ks = 0; ks < KSPLIT; ++ks) {
    f16x4 v = *(const f16x4*)(O16 + ((size_t)ks * T_DIM + q) * D_DIM + d0);
    o0 += wk[ks] * (float)v[0];
    o1 += wk[ks] * (float)v[1];
    o2 += wk[ks] * (float)v[2];
    o3 += wk[ks] * (float)v[3];
  }
  float4 o = {o0 * inv, o1 * inv, o2 * inv, o3 * inv};
  *(float4*)(Out + (size_t)q * D_DIM + d0) = o;
}

// ---- fallback (tiny ws): one wave per q row, fp32 streaming online softmax
__global__ void cboe_naive(const float* __restrict__ X, const float* __restrict__ E,
                           float* __restrict__ Out) {
  int row  = blockIdx.x * 4 + (threadIdx.x >> 6);
  int lane = threadIdx.x & 63;
  float xq[16], acc[16];
  #pragma unroll
  for (int j = 0; j < 16; ++j) {
    xq[j] = X[(size_t)row * D_DIM + lane*16 + j];
    acc[j] = 0.f;
  }
  float m = -1.0e30f, l = 0.f;
  for (int key = 0; key < N_DIM; ++key) {
    const float* er = E + (size_t)key * D_DIM + lane*16;
    float ev[16];
    float s = 0.f;
    #pragma unroll
    for (int j = 0; j < 16; ++j) { ev[j] = er[j]; s += xq[j] * ev[j]; }
    #pragma unroll
    for (int sh = 1; sh < 64; sh <<= 1) s += __shfl_xor(s, sh);
    float mn = fmaxf(m, s);
    float sc = __expf(m - mn);
    float p  = __expf(s - mn);
    l = l * sc + p;
    #pragma unroll
    for (int j = 0; j < 16; ++j) acc[j] = acc[j] * sc + p * ev[j];
    m = mn;
  }
  #pragma unroll
  for (int j = 0; j < 16; ++j)
    Out[(size_t)row * D_DIM + lane*16 + j] = acc[j] / l;
}

extern "C" void kernel_launch(void* const* d_in, const int* in_sizes, int n_in,
                              void* d_out, int out_size, void* d_ws, size_t ws_size,
                              hipStream_t stream) {
  const float* X  = (const float*)d_in[0];
  const float* Eg = (const float*)d_in[1];
  float* Out = (float*)d_out;

  const size_t szE16 = (size_t)N_DIM * D_DIM * sizeof(f16);            // 64 MiB
  const size_t szO16 = (size_t)KSPLIT * T_DIM * D_DIM * sizeof(f16);   // 32 MiB
  const size_t szML  = (size_t)KSPLIT * T_DIM * 2 * sizeof(float);     // 128 KiB
  const size_t need  = szE16 + szO16 + szML;

  if (!d_ws || ws_size < need) {
    cboe_naive<<<dim3(T_DIM/4), dim3(256), 0, stream>>>(X, Eg, Out);
    return;
  }

  char* p = (char*)d_ws;
  f16*   E16 = (f16*)p;   p += szE16;
  f16*   O16 = (f16*)p;   p += szO16;
  float* ML  = (float*)p;

  e16_build<<<dim3((N_DIM * D_DIM) / (256 * 8)), dim3(256), 0, stream>>>(Eg, E16);

  const int shmem = (int)sizeof(Lds);   // ~157 KB: opt in
  hipFuncSetAttribute(reinterpret_cast<const void*>(&cboe_attn),
                      hipFuncAttributeMaxDynamicSharedMemorySize, shmem);
  cboe_attn<<<dim3(NBLOCKS), dim3(512), shmem, stream>>>(X, E16, O16, ML);
  combine<<<dim3(T_DIM), dim3(256), 0, stream>>>(O16, ML, Out);
}

// Round 9
// 1938.080 us; speedup vs baseline: 2.1664x; 2.1664x over previous
//
#include <hip/hip_runtime.h>
#include <stdint.h>

#define T_DIM 4096
#define N_DIM 32768
#define D_DIM 1024
#define QB 64
#define KB 32
#define KSPLIT 4
#define ITERS (N_DIM / KSPLIT / KB)      // 256
#define NKB_TOT (N_DIM / KB)             // 1024
#define NKEYS_PER (N_DIM / KSPLIT)       // 8192
#define NBLOCKS ((T_DIM / QB) * KSPLIT)  // 256 = 1 block/CU

typedef _Float16 f16;
typedef _Float16 f16x8 __attribute__((ext_vector_type(8)));
typedef _Float16 f16x4 __attribute__((ext_vector_type(4)));
typedef float f32x4 __attribute__((ext_vector_type(4)));

#define SWZ(q, k0) ((k0) ^ ((((q) >> 2) & 3) << 2))

struct __align__(16) Lds {
  f16   K[2][KB * D_DIM];   // 131072 B : double-buffered K tile (swizzled)
  float Spart[2][QB][40];   //  20480 B : per-d-half score partials
  f16   P[QB][40];          //   5120 B
  float srow[QB];           //    256 B
  float linv[QB];           //    256 B
};                          // 157184 B -> 1 block/CU

// ---- precompute: E (fp32 row-major) -> E16 (fp16 row-major)
__global__ void e16_build(const float* __restrict__ E, f16* __restrict__ E16) {
  size_t i8 = (size_t)(blockIdx.x * 256 + threadIdx.x) * 8;
  float4 a = *(const float4*)(E + i8);
  float4 b = *(const float4*)(E + i8 + 4);
  f16x8 v = {(f16)a.x,(f16)a.y,(f16)a.z,(f16)a.w,
             (f16)b.x,(f16)b.y,(f16)b.z,(f16)b.w};
  *(f16x8*)(E16 + i8) = v;
}

// ---- precompute: W2[kb][d][k] = fp16(E[kb*32+k][d])  (key-major V tiles)
__global__ void w2_build(const float* __restrict__ E, f16* __restrict__ W2) {
  int kb = blockIdx.x >> 2;
  int dg = blockIdx.x & 3;
  int d  = dg * 256 + threadIdx.x;
  for (int kq = 0; kq < 4; ++kq) {
    int k0 = kq * 8;
    f16x8 v;
    #pragma unroll
    for (int j = 0; j < 8; ++j)
      v[j] = (f16)E[(size_t)(kb*32 + k0 + j) * D_DIM + d];
    *(f16x8*)(W2 + (size_t)kb * (D_DIM*KB) + (size_t)d*KB + k0) = v;
  }
}

__device__ __forceinline__ void gl_lds16(const void* g, void* l) {
  auto* gp = reinterpret_cast<const __attribute__((address_space(1))) uint32_t*>(
      reinterpret_cast<uintptr_t>(g));
  auto* lp = reinterpret_cast<__attribute__((address_space(3))) uint32_t*>(
      reinterpret_cast<uintptr_t>(l));
  __builtin_amdgcn_global_load_lds(gp, lp, 16, 0, 0);
}

// 512 thr = 8 waves, 1 block/CU (154 KB LDS). Wave (qt=w>>1, dh=w&1): QK^T for
// q-subtile qt over d-half dh (K from swizzled LDS, staged 2 iters ahead via
// global_load_lds, counted vmcnt -- never 0). Wave w owns d-slice w*128 for PV
// (V direct from W2, issued at B1, consumed after B2). Swizzle pair verified
// in r8 (passed): LDS[key*2048+doff] holds G[key*2048+(doff^((key&7)<<4))];
// read XORs the same mask. Frag maps (verified r1-r8): A row=lane&15,
// k=(lane>>4)*8+j; B col=lane&15; C row=4*(lane>>4)+r, col=lane&15.
__global__ __launch_bounds__(512, 1)
void cboe_attn(const float* __restrict__ X, const f16* __restrict__ E16,
               const f16* __restrict__ W2, f16* __restrict__ O16,
               float* __restrict__ ML)
{
  extern __shared__ char smem_raw[];
  Lds& L = *reinterpret_cast<Lds*>(smem_raw);
  const int tid  = threadIdx.x;
  const int lane = tid & 63;
  const int w    = tid >> 6;
  const int c    = lane & 15;
  const int g    = lane >> 4;
  const int qt   = w >> 1;        // QK q-subtile (16 rows)
  const int dh   = w & 1;         // QK d-half (512 d)
  const int wd   = w * 128;       // PV d-slice
  const int qtile = blockIdx.x & 63;
  const int ks    = blockIdx.x >> 6;    // natural mapping (r2: best locality)
  const int qb    = qtile * QB;
  const size_t key0 = (size_t)ks * NKEYS_PER;
  const int sq    = tid >> 3;     // softmax: q row 0..63 (8 thr/row)
  const int kslot = tid & 7;

  // Q frags: qf[kc] = X[qb+qt*16+c][dh*512 + kc*32 + g*8 ..+7]  (64 VGPR)
  f16x8 qf[16];
  {
    const float* qrow = X + (size_t)(qb + qt*16 + c) * D_DIM + dh*512;
    #pragma unroll
    for (int kc = 0; kc < 16; ++kc) {
      float4 a = *(const float4*)(qrow + kc*32 + g*8);
      float4 b = *(const float4*)(qrow + kc*32 + g*8 + 4);
      qf[kc] = (f16x8){(f16)a.x,(f16)a.y,(f16)a.z,(f16)a.w,
                       (f16)b.x,(f16)b.y,(f16)b.z,(f16)b.w};
    }
  }

  f32x4 acc[4][8];   // [q2][dt] over PV d-slice (128 AGPR)
  #pragma unroll
  for (int q2 = 0; q2 < 4; ++q2)
    #pragma unroll
    for (int dt = 0; dt < 8; ++dt) acc[q2][dt] = (f32x4){0.f,0.f,0.f,0.f};

  float m_run = -1.0e30f, l_run = 0.0f;

  // stage K tile IT into L.K[IT&1]: 8 insts/wave x 1 KB, source pre-swizzled
  #define STAGE(IT) do {                                                      \
    const char* gt_ = (const char*)(E16 + (key0 + (size_t)(IT)*KB)*D_DIM);    \
    char* lb_ = (char*)&L.K[(IT) & 1][0];                                     \
    _Pragma("unroll")                                                         \
    for (int r_ = 0; r_ < 8; ++r_) {                                          \
      uint32_t a_ = (uint32_t)(w*8192 + r_*1024 + lane*16);                   \
      uint32_t s_ = a_ ^ (((a_ >> 11) & 7) << 4);                             \
      gl_lds16(gt_ + s_, lb_ + w*8192 + r_*1024);                             \
    }                                                                         \
  } while (0)

  STAGE(0);
  STAGE(1);

  const int sxor  = (c & 7) << 4;
  const int dbase = dh*1024 + g*16;

  for (int it = 0; it < ITERS; ++it) {
    const char* KLB = (const char*)&L.K[it & 1][0];

    // ---- B0: stage(it) landed (stage(it+1) = 8 newest stay in flight)
    asm volatile("s_waitcnt vmcnt(8)" ::: "memory");
    __builtin_amdgcn_s_barrier();
    asm volatile("" ::: "memory");

    // ---- phase A: QK^T, q-subtile qt x d-half dh, K from swizzled LDS
    #pragma unroll
    for (int kt = 0; kt < 2; ++kt) {
      const int keyb = (kt*16 + c) << 11;
      f32x4 sA = (f32x4){0.f,0.f,0.f,0.f};
      f32x4 sB = (f32x4){0.f,0.f,0.f,0.f};
      __builtin_amdgcn_s_setprio(1);
      #pragma unroll
      for (int kc = 0; kc < 8; ++kc) {
        f16x8 ak0 = *(const f16x8*)(KLB + keyb + ((dbase + kc*64) ^ sxor));
        f16x8 ak1 = *(const f16x8*)(KLB + keyb + ((dbase + (kc+8)*64) ^ sxor));
        sA = __builtin_amdgcn_mfma_f32_16x16x32_f16(ak0, qf[kc],   sA, 0, 0, 0);
        sB = __builtin_amdgcn_mfma_f32_16x16x32_f16(ak1, qf[kc+8], sB, 0, 0, 0);
      }
      __builtin_amdgcn_s_setprio(0);
      f32x4 s = sA + sB;
      const int q = qt*16 + c;
      *(f32x4*)&L.Spart[dh][q][SWZ(q, kt*16 + g*4)] = s;
    }

    // ---- B1: Spart visible; K[it&1] reads complete (safe to overwrite)
    asm volatile("s_waitcnt lgkmcnt(0)" ::: "memory");
    __builtin_amdgcn_s_barrier();
    asm volatile("" ::: "memory");

    // issue V loads (older) then next-next K stage (newest stays in flight)
    const f16* vbase = W2 + (key0/KB + it) * (size_t)(D_DIM*KB);
    f16x8 bv[8];
    #pragma unroll
    for (int dt = 0; dt < 8; ++dt)
      bv[dt] = *(const f16x8*)(vbase + (size_t)(wd + dt*16 + c)*KB + g*8);
    if (it + 2 < ITERS) STAGE(it + 2);

    // ---- softmax: 8 threads/row, fold the 2 d-half partials
    f32x4 sv = *(const f32x4*)&L.Spart[0][sq][SWZ(sq, kslot*4)];
    sv += *(const f32x4*)&L.Spart[1][sq][SWZ(sq, kslot*4)];
    float tm = fmaxf(fmaxf(sv[0],sv[1]), fmaxf(sv[2],sv[3]));
    tm = fmaxf(tm, __shfl_xor(tm, 1));
    tm = fmaxf(tm, __shfl_xor(tm, 2));
    tm = fmaxf(tm, __shfl_xor(tm, 4));
    const bool upd = tm > m_run + 8.0f;            // T13 defer-max
    const float mn = upd ? tm : m_run;
    const float scale = upd ? __expf(m_run - mn) : 1.0f;
    float p0 = __expf(sv[0]-mn), p1 = __expf(sv[1]-mn);
    float p2 = __expf(sv[2]-mn), p3 = __expf(sv[3]-mn);
    *(f16x4*)&L.P[sq][kslot*4] = (f16x4){(f16)p0,(f16)p1,(f16)p2,(f16)p3};
    float ps = (p0+p1)+(p2+p3);
    ps += __shfl_xor(ps, 1);
    ps += __shfl_xor(ps, 2);
    ps += __shfl_xor(ps, 4);
    l_run = l_run * scale + ps;
    m_run = mn;
    if (kslot == 0) L.srow[sq] = scale;

    // ---- B2: P/srow visible
    asm volatile("s_waitcnt lgkmcnt(0)" ::: "memory");
    __builtin_amdgcn_s_barrier();
    asm volatile("" ::: "memory");

    // ---- phase C: gated rescale + PV (bv wait = vmcnt(8), stage flying)
    #pragma unroll
    for (int q2 = 0; q2 < 4; ++q2) {
      f32x4 sc = *(const f32x4*)&L.srow[q2*16 + g*4];
      bool need = (sc[0]!=1.f)|(sc[1]!=1.f)|(sc[2]!=1.f)|(sc[3]!=1.f);
      if (__any(need)) {
        #pragma unroll
        for (int dt = 0; dt < 8; ++dt) {
          acc[q2][dt][0]*=sc[0]; acc[q2][dt][1]*=sc[1];
          acc[q2][dt][2]*=sc[2]; acc[q2][dt][3]*=sc[3];
        }
      }
    }
    #pragma unroll
    for (int q2 = 0; q2 < 4; ++q2) {
      f16x8 ap = *(const f16x8*)&L.P[q2*16 + c][g*8];
      __builtin_amdgcn_s_setprio(1);
      #pragma unroll
      for (int dt = 0; dt < 8; ++dt)
        acc[q2][dt] = __builtin_amdgcn_mfma_f32_16x16x32_f16(ap, bv[dt], acc[q2][dt], 0, 0, 0);
      __builtin_amdgcn_s_setprio(0);
    }
    // K buffer hazard: stage(it+2) (issued post-B1) overwrites K[it&1],
    // whose ds_reads completed at B1. P/Spart cross-iter ordered by B0/B1.
  }
  #undef STAGE

  // ---- epilogue: normalized f16 partials + (m,l)
  if (kslot == 0) {
    size_t qg = (size_t)qb + sq;
    ML[((size_t)ks * T_DIM + qg) * 2 + 0] = m_run;
    ML[((size_t)ks * T_DIM + qg) * 2 + 1] = l_run;
    L.linv[sq] = 1.0f / l_run;
  }
  __syncthreads();
  #pragma unroll
  for (int q2 = 0; q2 < 4; ++q2) {
    f32x4 li = *(const f32x4*)&L.linv[q2*16 + g*4];
    #pragma unroll
    for (int dt = 0; dt < 8; ++dt)
      #pragma unroll
      for (int r = 0; r < 4; ++r)
        O16[((size_t)ks * T_DIM + qb + q2*16 + 4*g + r) * D_DIM + wd + dt*16 + c] =
            (f16)(acc[q2][dt][r] * li[r]);
  }
}

// ---- combine: out = sum_ks w_ks * O_ks, w_ks = l_ks e^{m_ks-M} / sum l e^{m-M}
__global__ void combine(const f16* __restrict__ O16, const float* __restrict__ ML,
                        float* __restrict__ Out) {
  int q  = blockIdx.x;
  int d0 = threadIdx.x * 4;
  float m[KSPLIT], l[KSPLIT];
  float M = -1.0e30f;
  #pragma unroll
  for (int ks = 0; ks < KSPLIT; ++ks) {
    m[ks] = ML[((size_t)ks * T_DIM + q) * 2 + 0];
    l[ks] = ML[((size_t)ks * T_DIM + q) * 2 + 1];
    M = fmaxf(M, m[ks]);
  }
  float W = 0.f, wk[KSPLIT];
  #pragma unroll
  for (int ks = 0; ks < KSPLIT; ++ks) {
    wk[ks] = l[ks] * __expf(m[ks] - M);
    W += wk[ks];
  }
  float inv = 1.0f / W;
  float o0 = 0.f, o1 = 0.f, o2 = 0.f, o3 = 0.f;
  #pragma unroll
  for (int ks = 0; ks < KSPLIT; ++ks) {
    f16x4 v = *(const f16x4*)(O16 + ((size_t)ks * T_DIM + q) * D_DIM + d0);
    o0 += wk[ks] * (float)v[0];
    o1 += wk[ks] * (float)v[1];
    o2 += wk[ks] * (float)v[2];
    o3 += wk[ks] * (float)v[3];
  }
  float4 o = {o0 * inv, o1 * inv, o2 * inv, o3 * inv};
  *(float4*)(Out + (size_t)q * D_DIM + d0) = o;
}

// ---- fallback (tiny ws): one wave per q row, fp32 streaming online softmax
__global__ void cboe_naive(const float* __restrict__ X, const float* __restrict__ E,
                           float* __restrict__ Out) {
  int row  = blockIdx.x * 4 + (threadIdx.x >> 6);
  int lane = threadIdx.x & 63;
  float xq[16], acc[16];
  #pragma unroll
  for (int j = 0; j < 16; ++j) {
    xq[j] = X[(size_t)row * D_DIM + lane*16 + j];
    acc[j] = 0.f;
  }
  float m = -1.0e30f, l = 0.f;
  for (int key = 0; key < N_DIM; ++key) {
    const float* er = E + (size_t)key * D_DIM + lane*16;
    float ev[16];
    float s = 0.f;
    #pragma unroll
    for (int j = 0; j < 16; ++j) { ev[j] = er[j]; s += xq[j] * ev[j]; }
    #pragma unroll
    for (int sh = 1; sh < 64; sh <<= 1) s += __shfl_xor(s, sh);
    float mn = fmaxf(m, s);
    float sc = __expf(m - mn);
    float p  = __expf(s - mn);
    l = l * sc + p;
    #pragma unroll
    for (int j = 0; j < 16; ++j) acc[j] = acc[j] * sc + p * ev[j];
    m = mn;
  }
  #pragma unroll
  for (int j = 0; j < 16; ++j)
    Out[(size_t)row * D_DIM + lane*16 + j] = acc[j] / l;
}

extern "C" void kernel_launch(void* const* d_in, const int* in_sizes, int n_in,
                              void* d_out, int out_size, void* d_ws, size_t ws_size,
                              hipStream_t stream) {
  const float* X  = (const float*)d_in[0];
  const float* Eg = (const float*)d_in[1];
  float* Out = (float*)d_out;

  const size_t szE16 = (size_t)N_DIM * D_DIM * sizeof(f16);            // 64 MiB
  const size_t szW2  = (size_t)NKB_TOT * D_DIM * KB * sizeof(f16);     // 64 MiB
  const size_t szO16 = (size_t)KSPLIT * T_DIM * D_DIM * sizeof(f16);   // 32 MiB
  const size_t szML  = (size_t)KSPLIT * T_DIM * 2 * sizeof(float);     // 128 KiB
  const size_t need  = szE16 + szW2 + szO16 + szML;

  if (!d_ws || ws_size < need) {
    cboe_naive<<<dim3(T_DIM/4), dim3(256), 0, stream>>>(X, Eg, Out);
    return;
  }

  char* p = (char*)d_ws;
  f16*   E16 = (f16*)p;   p += szE16;
  f16*   W2  = (f16*)p;   p += szW2;
  f16*   O16 = (f16*)p;   p += szO16;
  float* ML  = (float*)p;

  e16_build<<<dim3((N_DIM * D_DIM) / (256 * 8)), dim3(256), 0, stream>>>(Eg, E16);
  w2_build<<<dim3(NKB_TOT * 4), dim3(256), 0, stream>>>(Eg, W2);

  const int shmem = (int)sizeof(Lds);   // ~154 KB: opt in
  hipFuncSetAttribute(reinterpret_cast<const void*>(&cboe_attn),
                      hipFuncAttributeMaxDynamicSharedMemorySize, shmem);
  cboe_attn<<<dim3(NBLOCKS), dim3(512), shmem, stream>>>(X, E16, W2, O16, ML);
  combine<<<dim3(T_DIM), dim3(256), 0, stream>>>(O16, ML, Out);
}